// Round 20
// baseline (174.213 us; speedup 1.0000x reference)
//
#include <hip/hip_runtime.h>

#define NB 128
#define NN 50000
#define NE 300000
#define ND 256
#define NP 8

typedef __attribute__((ext_vector_type(4))) float f32x4;
typedef __attribute__((ext_vector_type(8))) short s16x8;

__device__ __forceinline__ unsigned short bf16rtn(float f) {
    unsigned int u = __float_as_uint(f);
    unsigned int r = (u + 0x7fffu + ((u >> 16) & 1u)) >> 16;
    return (unsigned short)r;
}

// one-instruction packed f32->bf16 (RNE, same rounding as bf16rtn)
__device__ __forceinline__ int cvtpk(float lo, float hi) {
    int r;
    asm("v_cvt_pk_bf16_f32 %0, %1, %2" : "=v"(r) : "v"(lo), "v"(hi));
    return r;
}

__device__ __forceinline__ s16x8 pack8(f32x4 a, f32x4 b) {
    union { int d[4]; s16x8 v; } u;
    u.d[0] = cvtpk(a[0], a[1]);
    u.d[1] = cvtpk(a[2], a[3]);
    u.d[2] = cvtpk(b[0], b[1]);
    u.d[3] = cvtpk(b[2], b[3]);
    return u.v;
}

__device__ __forceinline__ float eluf(float x) {
    return x > 0.f ? x : __expf(x) - 1.f;
}

// sum across the 16 lanes of a DPP row (VALU-only butterfly, no LDS).
__device__ __forceinline__ float rowsum16(float x) {
    int t;
    t = __builtin_amdgcn_update_dpp(0, __float_as_int(x), 0x121, 0xf, 0xf, true);
    x += __int_as_float(t);
    t = __builtin_amdgcn_update_dpp(0, __float_as_int(x), 0x122, 0xf, 0xf, true);
    x += __int_as_float(t);
    t = __builtin_amdgcn_update_dpp(0, __float_as_int(x), 0x124, 0xf, 0xf, true);
    x += __int_as_float(t);
    t = __builtin_amdgcn_update_dpp(0, __float_as_int(x), 0x128, 0xf, 0xf, true);
    x += __int_as_float(t);
    return x;
}

// ---- stage a 256x256 bf16 W matrix into LDS in FRAGMENT-MAJOR layout ------
// chunk i = [cg(16)][kk(8)][lane(64)] x 16B; read back contiguous 1KB per
// (cg,kk) -> ZERO bank conflicts (verified R12).
__device__ __forceinline__ void stage_W(char* Wl, const unsigned short* Wsrc,
                                        int tid, int nthr) {
    for (int i = tid; i < 8192; i += nthr) {
        int cg = i >> 9;
        int kk = (i >> 6) & 7;
        int ln = i & 63;
        const unsigned short* src =
            Wsrc + (size_t)(cg * 16 + (ln & 15)) * ND + kk * 32 + (ln >> 4) * 8;
        *(s16x8*)(Wl + i * 16) = *(const s16x8*)src;
    }
}

// ---- stage W_eff[b] = sum_p sim[b,p]*W_p into LDS fragment-major ---------
// reads W_p (2MB total, L2-resident, shared by all nodes blocks) directly;
// combines + cvt_pk on the fly -> no Weff materialization in HBM. Same RNE
// rounding as the old k_weff path (bitwise-identical output).
__device__ __forceinline__ void stage_Weff(char* Wl, const float* Wp,
                                           const float* s_, int tid, int nthr) {
    for (int i = tid; i < 8192; i += nthr) {
        int cg = i >> 9;
        int kk = (i >> 6) & 7;
        int ln = i & 63;
        const float* src =
            Wp + (size_t)(cg * 16 + (ln & 15)) * ND + kk * 32 + (ln >> 4) * 8;
        f32x4 g0 = {0.f, 0.f, 0.f, 0.f}, g1 = {0.f, 0.f, 0.f, 0.f};
#pragma unroll
        for (int p = 0; p < NP; ++p) {
            const float* sp = src + (size_t)p * ND * ND;
            f32x4 w0 = *(const f32x4*)sp;
            f32x4 w1 = *(const f32x4*)(sp + 4);
            float s = s_[p];
            g0[0] += s * w0[0]; g0[1] += s * w0[1];
            g0[2] += s * w0[2]; g0[3] += s * w0[3];
            g1[0] += s * w1[0]; g1[1] += s * w1[1];
            g1[2] += s * w1[2]; g1[3] += s * w1[3];
        }
        *(s16x8*)(Wl + i * 16) = pack8(g0, g1);
    }
}

// ---------------- fused prep kernel ----------------------------------------
// bid 0..63: W_edge f32->bf16 | bid 64+: starts/zero/dsc
__global__ __launch_bounds__(256) void k_prep(
    const float* __restrict__ We, unsigned short* __restrict__ Wbf,
    const int* __restrict__ nidx, int* __restrict__ starts,
    float* __restrict__ rel_logits,
    const int* __restrict__ eidx, const float* __restrict__ dist,
    float* __restrict__ dscg)
{
    int bid = blockIdx.x;
    int tid = threadIdx.x;
    if (bid < 64) {
        int i = (bid * 256 + tid) * 4;
        f32x4 v = *(const f32x4*)(We + i);
        Wbf[i + 0] = bf16rtn(v[0]); Wbf[i + 1] = bf16rtn(v[1]);
        Wbf[i + 2] = bf16rtn(v[2]); Wbf[i + 3] = bf16rtn(v[3]);
    } else {
        int n = (bid - 64) * 256 + tid;
        if (n < NE) dscg[n] = dist[eidx[n]];
        if (n >= NN) return;
        rel_logits[n] = 0.f;
        int cur = nidx[n];
        int prev = (n == 0) ? -1 : nidx[n - 1];
        for (int b2 = prev + 1; b2 <= cur; ++b2) starts[b2] = n;
        if (n == NN - 1)
            for (int b2 = cur + 1; b2 <= NB; ++b2) starts[b2] = NN;
    }
}

// ---------------- fused main kernel: edges (bid<256) + nodes (bid>=256) ----
// Edges branch: byte-identical to R18's (129.3us best): 1024 thr = 16 waves,
// 1 block/CU, W 128KB fragment-major LDS (0 conflicts), barrier-free
// per-wave 16-edge tile streams, balanced gw = wave*256+bid, cg loop
// unroll 1 (R12: full unroll spills), setprio(1) around MFMA cluster.
// [R19 lesson: 32-edge tiles at 8 waves lose to TLP; structure frozen.]
// Nodes branch: W_eff combined ON THE FLY during LDS staging (from L2-
// resident W_p) -- no HBM Weff materialization.
__global__ __launch_bounds__(1024, 4) void k_main(
    const float* __restrict__ instr, const float* __restrict__ dscg,
    const float* __restrict__ eattrs, const unsigned short* __restrict__ Wbf,
    const float* __restrict__ wrs, const int* __restrict__ ebidx,
    const int* __restrict__ eidx, float* __restrict__ rel_logits,
    const float* __restrict__ sim, const float* __restrict__ Wp,
    const float* __restrict__ nattrs, const float* __restrict__ wns,
    const int* __restrict__ starts, float* __restrict__ state_logits)
{
    __shared__ char Wl[131072];

    int tid = threadIdx.x;
    int lane = tid & 63;
    int wave = tid >> 6;      // 0..15
    int l15 = lane & 15;
    int q = lane >> 4;        // 0..3

    if (blockIdx.x < 256) {
        // ================= EDGES =================
        stage_W(Wl, Wbf, tid, 1024);
        __syncthreads();

        int gw = wave * 256 + blockIdx.x;         // balanced heavy/light mix
        const int NT = NE / 16;                   // 18750
        for (int t = gw; t < NT; t += 4096) {
            int e0 = t * 16;
            int e4 = e0 + 4 * q;
            int eb0 = ebidx[e4 + 0], eb1 = ebidx[e4 + 1];
            int eb2 = ebidx[e4 + 2], eb3 = ebidx[e4 + 3];
            float dv0 = dscg[e4 + 0], dv1 = dscg[e4 + 1];
            float dv2 = dscg[e4 + 2], dv3 = dscg[e4 + 3];
            int dd0 = eidx[NE + e4 + 0], dd1 = eidx[NE + e4 + 1];
            int dd2 = eidx[NE + e4 + 2], dd3 = eidx[NE + e4 + 3];

            const float* ib0 = instr + (size_t)eb0 * ND + l15;
            const float* ib1 = instr + (size_t)eb1 * ND + l15;
            const float* ib2 = instr + (size_t)eb2 * ND + l15;
            const float* ib3 = instr + (size_t)eb3 * ND + l15;

            const float* arow = eattrs + (size_t)(e0 + l15) * ND + q * 8;
            s16x8 afr[8];
#pragma unroll
            for (int kk = 0; kk < 8; ++kk) {
                f32x4 a0 = *(const f32x4*)(arow + kk * 32);
                f32x4 a1 = *(const f32x4*)(arow + kk * 32 + 4);
                afr[kk] = pack8(a0, a1);
            }

            float nv0 = ib0[0], nv1 = ib1[0], nv2 = ib2[0], nv3 = ib3[0];
            float nw = wrs[l15];

            float p0 = 0.f, p1 = 0.f, p2 = 0.f, p3 = 0.f;
#pragma unroll 1
            for (int cg = 0; cg < 16; ++cg) {
                float v0 = nv0, v1 = nv1, v2 = nv2, v3 = nv3, wvc = nw;
                int cn = (cg + 1 < 16 ? cg + 1 : 15) * 16;
                nv0 = ib0[cn]; nv1 = ib1[cn]; nv2 = ib2[cn]; nv3 = ib3[cn];
                nw = wrs[cn + l15];

                f32x4 acc = {0.f, 0.f, 0.f, 0.f};
                const char* fb = Wl + cg * 8192 + lane * 16;
                __builtin_amdgcn_s_setprio(1);
#pragma unroll
                for (int kk = 0; kk < 8; ++kk) {
                    s16x8 bf = *(const s16x8*)(fb + kk * 1024);
                    acc = __builtin_amdgcn_mfma_f32_16x16x32_bf16(afr[kk], bf, acc, 0, 0, 0);
                }
                __builtin_amdgcn_s_setprio(0);
                p0 += wvc * eluf(v0 * acc[0]);
                p1 += wvc * eluf(v1 * acc[1]);
                p2 += wvc * eluf(v2 * acc[2]);
                p3 += wvc * eluf(v3 * acc[3]);
            }
            p0 = rowsum16(p0); p1 = rowsum16(p1);
            p2 = rowsum16(p2); p3 = rowsum16(p3);
            if (l15 == 0) {
                atomicAdd(&rel_logits[dd0], dv0 * p0);
                atomicAdd(&rel_logits[dd1], dv1 * p1);
                atomicAdd(&rel_logits[dd2], dv2 * p2);
                atomicAdd(&rel_logits[dd3], dv3 * p3);
            }
        }
    } else {
        // ================= NODES =================
        int nb = blockIdx.x - 256;
        int b = nb >> 1;
        int half = nb & 1;
        int s0 = starts[b], s1 = starts[b + 1];
        int nt = (s1 - s0 + 15) >> 4;

        float s_[NP];
#pragma unroll
        for (int p = 0; p < NP; ++p) s_[p] = sim[b * NP + p];
        stage_Weff(Wl, Wp, s_, tid, 1024);
        __syncthreads();

        const float* irow = instr + (size_t)b * ND + l15;
        for (int t = half * 16 + wave; t < nt; t += 32) {
            int n0 = s0 + t * 16;
            int arn = n0 + l15;
            bool valid = arn < s1;
            const float* arow = nattrs + (size_t)arn * ND + q * 8;
            s16x8 afr[8];
#pragma unroll
            for (int kk = 0; kk < 8; ++kk) {
                f32x4 a0 = {0.f, 0.f, 0.f, 0.f}, a1 = {0.f, 0.f, 0.f, 0.f};
                if (valid) {
                    a0 = *(const f32x4*)(arow + kk * 32);
                    a1 = *(const f32x4*)(arow + kk * 32 + 4);
                }
                afr[kk] = pack8(a0, a1);
            }

            float p0 = 0.f, p1 = 0.f, p2 = 0.f, p3 = 0.f;
#pragma unroll 1
            for (int cg = 0; cg < 16; ++cg) {
                f32x4 acc = {0.f, 0.f, 0.f, 0.f};
                const char* fb = Wl + cg * 8192 + lane * 16;
                __builtin_amdgcn_s_setprio(1);
#pragma unroll
                for (int kk = 0; kk < 8; ++kk) {
                    s16x8 bf = *(const s16x8*)(fb + kk * 1024);
                    acc = __builtin_amdgcn_mfma_f32_16x16x32_bf16(afr[kk], bf, acc, 0, 0, 0);
                }
                __builtin_amdgcn_s_setprio(0);
                int c = cg * 16;
                float ivc = irow[c];
                float wvc = wns[c + l15];
                p0 += wvc * eluf(ivc * acc[0]);
                p1 += wvc * eluf(ivc * acc[1]);
                p2 += wvc * eluf(ivc * acc[2]);
                p3 += wvc * eluf(ivc * acc[3]);
            }
            p0 = rowsum16(p0); p1 = rowsum16(p1);
            p2 = rowsum16(p2); p3 = rowsum16(p3);
            if (l15 == 0) {
                int n = n0 + 4 * q;
                if (n + 0 < s1) state_logits[n + 0] = p0;
                if (n + 1 < s1) state_logits[n + 1] = p1;
                if (n + 2 < s1) state_logits[n + 2] = p2;
                if (n + 3 < s1) state_logits[n + 3] = p3;
            }
        }
    }
}

// ---------------- per-graph softmaxes + final mix -------------------------
__global__ __launch_bounds__(256) void k_softmax_mix(
    const float* __restrict__ state_l, const float* __restrict__ rel_l,
    const int* __restrict__ starts, const float* __restrict__ relsim,
    float* __restrict__ out)
{
    __shared__ float wms[4], wmr[4], wss[4], wsr[4];
    int b = blockIdx.x;
    int s0 = starts[b], s1 = starts[b + 1];
    if (s1 <= s0) return;
    int tid = threadIdx.x, lane = tid & 63, wave = tid >> 6;

    float ms = -3.4e38f, mr = -3.4e38f;
    for (int n = s0 + tid; n < s1; n += 256) {
        ms = fmaxf(ms, state_l[n]);
        mr = fmaxf(mr, rel_l[n]);
    }
#pragma unroll
    for (int m = 1; m < 64; m <<= 1) {
        ms = fmaxf(ms, __shfl_xor(ms, m, 64));
        mr = fmaxf(mr, __shfl_xor(mr, m, 64));
    }
    if (lane == 0) { wms[wave] = ms; wmr[wave] = mr; }
    __syncthreads();
    ms = fmaxf(fmaxf(wms[0], wms[1]), fmaxf(wms[2], wms[3]));
    mr = fmaxf(fmaxf(wmr[0], wmr[1]), fmaxf(wmr[2], wmr[3]));

    float ss = 0.f, sr = 0.f;
    for (int n = s0 + tid; n < s1; n += 256) {
        ss += __expf(state_l[n] - ms);
        sr += __expf(rel_l[n] - mr);
    }
#pragma unroll
    for (int m = 1; m < 64; m <<= 1) {
        ss += __shfl_xor(ss, m, 64);
        sr += __shfl_xor(sr, m, 64);
    }
    if (lane == 0) { wss[wave] = ss; wsr[wave] = sr; }
    __syncthreads();
    ss = wss[0] + wss[1] + wss[2] + wss[3];
    sr = wsr[0] + wsr[1] + wsr[2] + wsr[3];

    float rb = relsim[b];
    float iss = 1.f / ss, isr = 1.f / sr;
    for (int n = s0 + tid; n < s1; n += 256) {
        out[n] = rb * __expf(rel_l[n] - mr) * isr
               + (1.f - rb) * __expf(state_l[n] - ms) * iss;
    }
}

extern "C" void kernel_launch(void* const* d_in, const int* in_sizes, int n_in,
                              void* d_out, int out_size, void* d_ws, size_t ws_size,
                              hipStream_t stream) {
    const float* instr  = (const float*)d_in[0];
    const float* dist   = (const float*)d_in[1];
    const float* sim    = (const float*)d_in[2];
    const float* relsim = (const float*)d_in[3];
    const float* nattr  = (const float*)d_in[4];
    const float* eattr  = (const float*)d_in[5];
    const float* Wp     = (const float*)d_in[6];
    const float* We     = (const float*)d_in[7];
    const float* wns    = (const float*)d_in[8];
    const float* wrs    = (const float*)d_in[9];
    const int* nidx     = (const int*)d_in[10];
    const int* ebidx    = (const int*)d_in[11];
    const int* eidx     = (const int*)d_in[12];
    float* out = (float*)d_out;

    char* ws = (char*)d_ws;
    float* rel_logits   = (float*)ws;                      // NN f @ 0
    float* state_logits = rel_logits + NN;                 // NN f @ 200000
    int* starts         = (int*)(ws + 400000);             // B+1 ints
    unsigned short* Wbf = (unsigned short*)(ws + 400640);  // 256*256 bf16
    float* dscg         = (float*)(ws + 532480);           // NE floats (1.2MB)

    k_prep<<<64 + (NE + 255) / 256, 256, 0, stream>>>(
        We, Wbf, nidx, starts, rel_logits, eidx, dist, dscg);
    k_main<<<512, 1024, 0, stream>>>(instr, dscg, eattr, Wbf, wrs, ebidx, eidx,
                                     rel_logits, sim, Wp, nattr, wns, starts,
                                     state_logits);
    k_softmax_mix<<<NB, 256, 0, stream>>>(state_logits, rel_logits, starts,
                                          relsim, out);
}

// Round 21
// 128.891 us; speedup vs baseline: 1.3516x; 1.3516x over previous
//
#include <hip/hip_runtime.h>

#define NB 128
#define NN 50000
#define NE 300000
#define ND 256
#define NP 8

typedef __attribute__((ext_vector_type(4))) float f32x4;
typedef __attribute__((ext_vector_type(8))) short s16x8;

__device__ __forceinline__ unsigned short bf16rtn(float f) {
    unsigned int u = __float_as_uint(f);
    unsigned int r = (u + 0x7fffu + ((u >> 16) & 1u)) >> 16;
    return (unsigned short)r;
}

// one-instruction packed f32->bf16 (RNE, same rounding as bf16rtn)
__device__ __forceinline__ int cvtpk(float lo, float hi) {
    int r;
    asm("v_cvt_pk_bf16_f32 %0, %1, %2" : "=v"(r) : "v"(lo), "v"(hi));
    return r;
}

__device__ __forceinline__ s16x8 pack8(f32x4 a, f32x4 b) {
    union { int d[4]; s16x8 v; } u;
    u.d[0] = cvtpk(a[0], a[1]);
    u.d[1] = cvtpk(a[2], a[3]);
    u.d[2] = cvtpk(b[0], b[1]);
    u.d[3] = cvtpk(b[2], b[3]);
    return u.v;
}

__device__ __forceinline__ float eluf(float x) {
    return x > 0.f ? x : __expf(x) - 1.f;
}

// sum across the 16 lanes of a DPP row (VALU-only butterfly, no LDS).
__device__ __forceinline__ float rowsum16(float x) {
    int t;
    t = __builtin_amdgcn_update_dpp(0, __float_as_int(x), 0x121, 0xf, 0xf, true);
    x += __int_as_float(t);
    t = __builtin_amdgcn_update_dpp(0, __float_as_int(x), 0x122, 0xf, 0xf, true);
    x += __int_as_float(t);
    t = __builtin_amdgcn_update_dpp(0, __float_as_int(x), 0x124, 0xf, 0xf, true);
    x += __int_as_float(t);
    t = __builtin_amdgcn_update_dpp(0, __float_as_int(x), 0x128, 0xf, 0xf, true);
    x += __int_as_float(t);
    return x;
}

// ---- stage a 256x256 bf16 W matrix into LDS in FRAGMENT-MAJOR layout ------
// chunk i = [cg(16)][kk(8)][lane(64)] x 16B; read back contiguous 1KB per
// (cg,kk) -> ZERO bank conflicts (verified R12).
__device__ __forceinline__ void stage_W(char* Wl, const unsigned short* Wsrc,
                                        int tid, int nthr) {
    for (int i = tid; i < 8192; i += nthr) {
        int cg = i >> 9;
        int kk = (i >> 6) & 7;
        int ln = i & 63;
        const unsigned short* src =
            Wsrc + (size_t)(cg * 16 + (ln & 15)) * ND + kk * 32 + (ln >> 4) * 8;
        *(s16x8*)(Wl + i * 16) = *(const s16x8*)src;
    }
}

// ---------------- fused prep kernel ----------------------------------------
// bid 0..63: W_edge f32->bf16 | 64..319: W_eff combine | 320+: starts/zero/dsc
// NOTE (R20 lesson): W_eff MUST be materialized here, not fused into k_main's
// nodes branch -- the fused combine perturbed k_main's shared register
// allocation (VGPR 88->56) and slowed the byte-identical edges loop 2x.
__global__ __launch_bounds__(256) void k_prep(
    const float* __restrict__ We, unsigned short* __restrict__ Wbf,
    const float* __restrict__ sim, const float* __restrict__ Wp,
    unsigned short* __restrict__ Weff,
    const int* __restrict__ nidx, int* __restrict__ starts,
    float* __restrict__ rel_logits,
    const int* __restrict__ eidx, const float* __restrict__ dist,
    float* __restrict__ dscg)
{
    int bid = blockIdx.x;
    int tid = threadIdx.x;
    if (bid < 64) {
        int i = (bid * 256 + tid) * 4;
        f32x4 v = *(const f32x4*)(We + i);
        Wbf[i + 0] = bf16rtn(v[0]); Wbf[i + 1] = bf16rtn(v[1]);
        Wbf[i + 2] = bf16rtn(v[2]); Wbf[i + 3] = bf16rtn(v[3]);
    } else if (bid < 320) {
        int wb = bid - 64;
        int chunk = (wb & 31) * 256 + tid;
        int off = chunk * 8;
        float wp[NP][8];
#pragma unroll
        for (int p = 0; p < NP; ++p) {
            const float* src = Wp + (size_t)p * ND * ND + off;
            f32x4 w0 = *(const f32x4*)src;
            f32x4 w1 = *(const f32x4*)(src + 4);
            wp[p][0] = w0[0]; wp[p][1] = w0[1]; wp[p][2] = w0[2]; wp[p][3] = w0[3];
            wp[p][4] = w1[0]; wp[p][5] = w1[1]; wp[p][6] = w1[2]; wp[p][7] = w1[3];
        }
        int b0 = (wb >> 5) * 16;
        for (int bb = 0; bb < 16; ++bb) {
            int b = b0 + bb;
            float g[8] = {0.f, 0.f, 0.f, 0.f, 0.f, 0.f, 0.f, 0.f};
#pragma unroll
            for (int p = 0; p < NP; ++p) {
                float s = sim[b * NP + p];
#pragma unroll
                for (int j = 0; j < 8; ++j) g[j] += s * wp[p][j];
            }
            s16x8 v;
#pragma unroll
            for (int j = 0; j < 8; ++j) v[j] = (short)bf16rtn(g[j]);
            *(s16x8*)(Weff + (size_t)b * ND * ND + off) = v;
        }
    } else {
        int n = (bid - 320) * 256 + tid;
        if (n < NE) dscg[n] = dist[eidx[n]];
        if (n >= NN) return;
        rel_logits[n] = 0.f;
        int cur = nidx[n];
        int prev = (n == 0) ? -1 : nidx[n - 1];
        for (int b2 = prev + 1; b2 <= cur; ++b2) starts[b2] = n;
        if (n == NN - 1)
            for (int b2 = cur + 1; b2 <= NB; ++b2) starts[b2] = NN;
    }
}

// ---------------- fused main kernel: edges (bid<256) + nodes (bid>=256) ----
// Edges blocks dispatch first (long pole, 1 block/CU at 128KB LDS); CUs that
// finish backfill with nodes blocks -> k_nodes + edge-tail overlap.
// Edges: barrier-free per-wave 16-edge tile streams, W fragment-major in LDS
// (0 bank conflicts), cg loop unroll 1 (R12: full unroll spills).
// gw = wave*256+bid BALANCED (R14's bid*16+wave put all 5-tile waves on
// blocks 0-147 -> 25% CU imbalance; now each block has ~9 heavy/7 light).
// s_setprio(1) around MFMA cluster (m191: helps independent-wave kernels).
// FROZEN per R15/R19/R20: 16-edge tiles, 16 waves, no source changes here.
__global__ __launch_bounds__(1024, 4) void k_main(
    const float* __restrict__ instr, const float* __restrict__ dscg,
    const float* __restrict__ eattrs, const unsigned short* __restrict__ Wbf,
    const float* __restrict__ wrs, const int* __restrict__ ebidx,
    const int* __restrict__ eidx, float* __restrict__ rel_logits,
    const unsigned short* __restrict__ Weff, const float* __restrict__ nattrs,
    const float* __restrict__ wns, const int* __restrict__ starts,
    float* __restrict__ state_logits)
{
    __shared__ char Wl[131072];

    int tid = threadIdx.x;
    int lane = tid & 63;
    int wave = tid >> 6;      // 0..15
    int l15 = lane & 15;
    int q = lane >> 4;        // 0..3

    if (blockIdx.x < 256) {
        // ================= EDGES =================
        stage_W(Wl, Wbf, tid, 1024);
        __syncthreads();

        int gw = wave * 256 + blockIdx.x;         // balanced heavy/light mix
        const int NT = NE / 16;                   // 18750
        for (int t = gw; t < NT; t += 4096) {
            int e0 = t * 16;
            int e4 = e0 + 4 * q;
            int eb0 = ebidx[e4 + 0], eb1 = ebidx[e4 + 1];
            int eb2 = ebidx[e4 + 2], eb3 = ebidx[e4 + 3];
            float dv0 = dscg[e4 + 0], dv1 = dscg[e4 + 1];
            float dv2 = dscg[e4 + 2], dv3 = dscg[e4 + 3];
            int dd0 = eidx[NE + e4 + 0], dd1 = eidx[NE + e4 + 1];
            int dd2 = eidx[NE + e4 + 2], dd3 = eidx[NE + e4 + 3];

            const float* ib0 = instr + (size_t)eb0 * ND + l15;
            const float* ib1 = instr + (size_t)eb1 * ND + l15;
            const float* ib2 = instr + (size_t)eb2 * ND + l15;
            const float* ib3 = instr + (size_t)eb3 * ND + l15;

            const float* arow = eattrs + (size_t)(e0 + l15) * ND + q * 8;
            s16x8 afr[8];
#pragma unroll
            for (int kk = 0; kk < 8; ++kk) {
                f32x4 a0 = *(const f32x4*)(arow + kk * 32);
                f32x4 a1 = *(const f32x4*)(arow + kk * 32 + 4);
                afr[kk] = pack8(a0, a1);
            }

            float nv0 = ib0[0], nv1 = ib1[0], nv2 = ib2[0], nv3 = ib3[0];
            float nw = wrs[l15];

            float p0 = 0.f, p1 = 0.f, p2 = 0.f, p3 = 0.f;
#pragma unroll 1
            for (int cg = 0; cg < 16; ++cg) {
                float v0 = nv0, v1 = nv1, v2 = nv2, v3 = nv3, wvc = nw;
                int cn = (cg + 1 < 16 ? cg + 1 : 15) * 16;
                nv0 = ib0[cn]; nv1 = ib1[cn]; nv2 = ib2[cn]; nv3 = ib3[cn];
                nw = wrs[cn + l15];

                f32x4 acc = {0.f, 0.f, 0.f, 0.f};
                const char* fb = Wl + cg * 8192 + lane * 16;
                __builtin_amdgcn_s_setprio(1);
#pragma unroll
                for (int kk = 0; kk < 8; ++kk) {
                    s16x8 bf = *(const s16x8*)(fb + kk * 1024);
                    acc = __builtin_amdgcn_mfma_f32_16x16x32_bf16(afr[kk], bf, acc, 0, 0, 0);
                }
                __builtin_amdgcn_s_setprio(0);
                p0 += wvc * eluf(v0 * acc[0]);
                p1 += wvc * eluf(v1 * acc[1]);
                p2 += wvc * eluf(v2 * acc[2]);
                p3 += wvc * eluf(v3 * acc[3]);
            }
            p0 = rowsum16(p0); p1 = rowsum16(p1);
            p2 = rowsum16(p2); p3 = rowsum16(p3);
            if (l15 == 0) {
                atomicAdd(&rel_logits[dd0], dv0 * p0);
                atomicAdd(&rel_logits[dd1], dv1 * p1);
                atomicAdd(&rel_logits[dd2], dv2 * p2);
                atomicAdd(&rel_logits[dd3], dv3 * p3);
            }
        }
    } else {
        // ================= NODES =================
        int nb = blockIdx.x - 256;
        int b = nb >> 1;
        int half = nb & 1;
        int s0 = starts[b], s1 = starts[b + 1];
        int nt = (s1 - s0 + 15) >> 4;

        stage_W(Wl, Weff + (size_t)b * ND * ND, tid, 1024);
        __syncthreads();

        const float* irow = instr + (size_t)b * ND + l15;
        for (int t = half * 16 + wave; t < nt; t += 32) {
            int n0 = s0 + t * 16;
            int arn = n0 + l15;
            bool valid = arn < s1;
            const float* arow = nattrs + (size_t)arn * ND + q * 8;
            s16x8 afr[8];
#pragma unroll
            for (int kk = 0; kk < 8; ++kk) {
                f32x4 a0 = {0.f, 0.f, 0.f, 0.f}, a1 = {0.f, 0.f, 0.f, 0.f};
                if (valid) {
                    a0 = *(const f32x4*)(arow + kk * 32);
                    a1 = *(const f32x4*)(arow + kk * 32 + 4);
                }
                afr[kk] = pack8(a0, a1);
            }

            float p0 = 0.f, p1 = 0.f, p2 = 0.f, p3 = 0.f;
#pragma unroll 1
            for (int cg = 0; cg < 16; ++cg) {
                f32x4 acc = {0.f, 0.f, 0.f, 0.f};
                const char* fb = Wl + cg * 8192 + lane * 16;
                __builtin_amdgcn_s_setprio(1);
#pragma unroll
                for (int kk = 0; kk < 8; ++kk) {
                    s16x8 bf = *(const s16x8*)(fb + kk * 1024);
                    acc = __builtin_amdgcn_mfma_f32_16x16x32_bf16(afr[kk], bf, acc, 0, 0, 0);
                }
                __builtin_amdgcn_s_setprio(0);
                int c = cg * 16;
                float ivc = irow[c];
                float wvc = wns[c + l15];
                p0 += wvc * eluf(ivc * acc[0]);
                p1 += wvc * eluf(ivc * acc[1]);
                p2 += wvc * eluf(ivc * acc[2]);
                p3 += wvc * eluf(ivc * acc[3]);
            }
            p0 = rowsum16(p0); p1 = rowsum16(p1);
            p2 = rowsum16(p2); p3 = rowsum16(p3);
            if (l15 == 0) {
                int n = n0 + 4 * q;
                if (n + 0 < s1) state_logits[n + 0] = p0;
                if (n + 1 < s1) state_logits[n + 1] = p1;
                if (n + 2 < s1) state_logits[n + 2] = p2;
                if (n + 3 < s1) state_logits[n + 3] = p3;
            }
        }
    }
}

// ---------------- per-graph softmaxes + final mix -------------------------
__global__ __launch_bounds__(256) void k_softmax_mix(
    const float* __restrict__ state_l, const float* __restrict__ rel_l,
    const int* __restrict__ starts, const float* __restrict__ relsim,
    float* __restrict__ out)
{
    __shared__ float wms[4], wmr[4], wss[4], wsr[4];
    int b = blockIdx.x;
    int s0 = starts[b], s1 = starts[b + 1];
    if (s1 <= s0) return;
    int tid = threadIdx.x, lane = tid & 63, wave = tid >> 6;

    float ms = -3.4e38f, mr = -3.4e38f;
    for (int n = s0 + tid; n < s1; n += 256) {
        ms = fmaxf(ms, state_l[n]);
        mr = fmaxf(mr, rel_l[n]);
    }
#pragma unroll
    for (int m = 1; m < 64; m <<= 1) {
        ms = fmaxf(ms, __shfl_xor(ms, m, 64));
        mr = fmaxf(mr, __shfl_xor(mr, m, 64));
    }
    if (lane == 0) { wms[wave] = ms; wmr[wave] = mr; }
    __syncthreads();
    ms = fmaxf(fmaxf(wms[0], wms[1]), fmaxf(wms[2], wms[3]));
    mr = fmaxf(fmaxf(wmr[0], wmr[1]), fmaxf(wmr[2], wmr[3]));

    float ss = 0.f, sr = 0.f;
    for (int n = s0 + tid; n < s1; n += 256) {
        ss += __expf(state_l[n] - ms);
        sr += __expf(rel_l[n] - mr);
    }
#pragma unroll
    for (int m = 1; m < 64; m <<= 1) {
        ss += __shfl_xor(ss, m, 64);
        sr += __shfl_xor(sr, m, 64);
    }
    if (lane == 0) { wss[wave] = ss; wsr[wave] = sr; }
    __syncthreads();
    ss = wss[0] + wss[1] + wss[2] + wss[3];
    sr = wsr[0] + wsr[1] + wsr[2] + wsr[3];

    float rb = relsim[b];
    float iss = 1.f / ss, isr = 1.f / sr;
    for (int n = s0 + tid; n < s1; n += 256) {
        out[n] = rb * __expf(rel_l[n] - mr) * isr
               + (1.f - rb) * __expf(state_l[n] - ms) * iss;
    }
}

extern "C" void kernel_launch(void* const* d_in, const int* in_sizes, int n_in,
                              void* d_out, int out_size, void* d_ws, size_t ws_size,
                              hipStream_t stream) {
    const float* instr  = (const float*)d_in[0];
    const float* dist   = (const float*)d_in[1];
    const float* sim    = (const float*)d_in[2];
    const float* relsim = (const float*)d_in[3];
    const float* nattr  = (const float*)d_in[4];
    const float* eattr  = (const float*)d_in[5];
    const float* Wp     = (const float*)d_in[6];
    const float* We     = (const float*)d_in[7];
    const float* wns    = (const float*)d_in[8];
    const float* wrs    = (const float*)d_in[9];
    const int* nidx     = (const int*)d_in[10];
    const int* ebidx    = (const int*)d_in[11];
    const int* eidx     = (const int*)d_in[12];
    float* out = (float*)d_out;

    char* ws = (char*)d_ws;
    float* rel_logits   = (float*)ws;                      // NN f @ 0
    float* state_logits = rel_logits + NN;                 // NN f @ 200000
    int* starts         = (int*)(ws + 400000);             // B+1 ints
    unsigned short* Wbf = (unsigned short*)(ws + 400640);  // 256*256 bf16
    unsigned short* Weff= (unsigned short*)(ws + 532480);  // 128*256*256 bf16 (16.8MB)
    float* dscg         = (float*)(ws + 17309696);         // NE floats (1.2MB)

    k_prep<<<320 + (NE + 255) / 256, 256, 0, stream>>>(
        We, Wbf, sim, Wp, Weff, nidx, starts, rel_logits, eidx, dist, dscg);
    k_main<<<512, 1024, 0, stream>>>(instr, dscg, eattr, Wbf, wrs, ebidx, eidx,
                                     rel_logits, Weff, nattr, wns, starts,
                                     state_logits);
    k_softmax_mix<<<NB, 256, 0, stream>>>(state_logits, rel_logits, starts,
                                          relsim, out);
}